// Round 1
// 2075.132 us; speedup vs baseline: 4.0323x; 4.0323x over previous
//
#include <hip/hip_runtime.h>
#include <stdint.h>

typedef unsigned short u16;
typedef short short8 __attribute__((ext_vector_type(8)));
typedef float f32x4 __attribute__((ext_vector_type(4)));

#define NS 256
#define CIN 2304
#define CH 512
#define HW 49
#define MTOT (NS*HW)   // 12544

__device__ __forceinline__ float b2f(u16 u){
    union { unsigned int v; float f; } x; x.v = ((unsigned int)u) << 16; return x.f;
}
__device__ __forceinline__ u16 f2b(float f){
    unsigned int u = __builtin_bit_cast(unsigned int, f);
    u += 0x7FFFu + ((u >> 16) & 1u);
    return (u16)(u >> 16);
}
__device__ __forceinline__ u16 load_as_bf16(const void* p, size_t i, int isf32){
    return isf32 ? f2b(((const float*)p)[i]) : ((const u16*)p)[i];
}

// async global->LDS, 16B per lane. Dest is wave-uniform base + lane*16 (HW rule).
__device__ __forceinline__ void gload16(const u16* g, u16* l){
    __builtin_amdgcn_global_load_lds((const __attribute__((address_space(1))) void*)g,
                                     (__attribute__((address_space(3))) void*)l,
                                     16, 0, 0);
}

// ---------------- dtype detector: fp32 mantissa halves have big exponents ----
__global__ void k_detect(const u16* __restrict__ src, int* __restrict__ flag){
    int cnt = 0;
    for (int i = threadIdx.x; i < 8192; i += 256){
        int e = (src[i] >> 7) & 0xFF;
        cnt += (e >= 0x90);
    }
    for (int off = 32; off; off >>= 1) cnt += __shfl_down(cnt, off, 64);
    __shared__ int sh[4];
    int wave = threadIdx.x >> 6, lane = threadIdx.x & 63;
    if (lane == 0) sh[wave] = cnt;
    __syncthreads();
    if (threadIdx.x == 0)
        flag[0] = (sh[0] + sh[1] + sh[2] + sh[3] > 200) ? 1 : 0;
}

// ---------------- zero filler ------------------------------------------------
__global__ void k_zero(u16* __restrict__ p, int n){
    int i = blockIdx.x*256 + threadIdx.x;
    if (i < n) p[i] = 0;
}

// ---------------- small converter (to bf16) ----------------------------------
__global__ void k_convert_small(const void* __restrict__ src, u16* __restrict__ dst,
                                int n, const int* __restrict__ flag){
    const int isf32 = flag[0];
    for (int i = blockIdx.x*256 + threadIdx.x; i < n; i += gridDim.x*256)
        dst[i] = load_as_bf16(src, i, isf32);
}

// ---------------- transpose bbox_feat [n][2304][49] -> in_t [n][49][2304] ----
__global__ void k_transpose_in(const void* __restrict__ src, u16* __restrict__ dst,
                               const int* __restrict__ flag){
    const int isf32 = flag[0];
    __shared__ u16 tile[64*50];
    const int n = blockIdx.x;
    const int c0 = blockIdx.y * 64;
    const size_t sbase = ((size_t)n*CIN + c0)*HW;
    for (int idx = threadIdx.x; idx < 64*49; idx += 256){
        int cc = idx / 49, hw = idx - cc*49;
        tile[cc*50 + hw] = load_as_bf16(src, sbase + cc*HW + hw, isf32);
    }
    __syncthreads();
    u16* d = dst + (size_t)n*HW*CIN + c0;
    for (int idx = threadIdx.x; idx < 49*64; idx += 256){
        int hw = idx >> 6, cc = idx & 63;
        d[(size_t)hw*CIN + cc] = tile[cc*50 + hw];
    }
}

// ---------------- weight transpose [512][Cin][9] -> [512][9][Cin] ------------
__global__ void k_transpose_w(const void* __restrict__ w, u16* __restrict__ wt,
                              int Cin, const int* __restrict__ flag){
    const int isf32 = flag[0];
    size_t total = (size_t)CH * Cin * 9;
    for (size_t d = (size_t)blockIdx.x*blockDim.x + threadIdx.x; d < total;
         d += (size_t)gridDim.x*blockDim.x){
        int c  = (int)(d % Cin);
        size_t t = d / Cin;
        int kk = (int)(t % 9);
        int co = (int)(t / 9);
        wt[d] = load_as_bf16(w, ((size_t)co*Cin + c)*9 + kk, isf32);
    }
}

// ---------------- 3x3 pad-1 conv as implicit GEMM (m97-style MFMA pipeline) --
// Tile 128x128, BK=64, 4 waves (2x2), 4x4 16x16x32 frags per wave.
// A staged via global_load_lds with XOR-swizzled SOURCE (linear LDS dest),
// reads use the matching swizzled ds_read_b128 slot. Padding taps read zpage.
// mode 0: out_cl[(co>>9)*MTOT*CH + m*CH + (co&511)] = acc   (allows N=1024 KV fusion)
// mode 1: out[branch][n][co][hw] = acc + feat_res[m][co], dtype per dtf
__global__ __launch_bounds__(256) void k_conv3x3(
        const u16* __restrict__ in_t, const u16* __restrict__ w_t, int Cin,
        const u16* __restrict__ zpage,
        u16* __restrict__ out_cl,
        const u16* __restrict__ feat_res, void* __restrict__ out_base,
        int mode, int branch, const int* __restrict__ dtf)
{
    __shared__ __align__(16) u16 As[128*64];
    __shared__ __align__(16) u16 Bs[128*64];
    const int tid  = threadIdx.x;
    const int wave = tid >> 6, lane = tid & 63;
    const int m0  = blockIdx.x * 128;
    const int co0 = blockIdx.y * 128;

    // ---- loader mapping: thread t covers LDS rows (t>>3)+32s, 16B slot t&7 ----
    const int lr  = tid >> 3;                 // 0..31
    const int sl  = tid & 7;                  // 16B slot within 128B row
    const int swz = (sl ^ (lr & 7)) * 8;      // pre-swizzled source elem offset

    int nA[4], yA[4], xA[4];
#pragma unroll
    for (int s = 0; s < 4; ++s){
        int m = m0 + lr + 32*s;
        nA[s] = m / 49;
        int hw = m - nA[s]*49;
        yA[s] = hw / 7; xA[s] = hw - yA[s]*7;
    }
    const u16* bRow[4];
#pragma unroll
    for (int s = 0; s < 4; ++s)
        bRow[s] = w_t + (size_t)(co0 + lr + 32*s)*9*Cin + swz;

    // wave-uniform LDS staging bases (rows 8*wave + 32*s)
    u16* ldsA[4]; u16* ldsB[4];
#pragma unroll
    for (int s = 0; s < 4; ++s){
        ldsA[s] = &As[(wave*8 + s*32)*64];
        ldsB[s] = &Bs[(wave*8 + s*32)*64];
    }

    f32x4 acc[4][4];
#pragma unroll
    for (int i = 0; i < 4; ++i)
#pragma unroll
        for (int j = 0; j < 4; ++j)
            acc[i][j] = (f32x4){0.f, 0.f, 0.f, 0.f};

    const int wm = (wave & 1) * 64, wn = (wave >> 1) * 64;
    // frag read: row = w* + i*16 + (lane&15); row&7 == lane&7
    const int rA0 = wm + (lane & 15);
    const int rB0 = wn + (lane & 15);
    const int sl0 = (((lane >> 4)    ) ^ (lane & 7)) * 8;  // k-half 0 slot (elems)
    const int sl1 = ((4 + (lane >> 4)) ^ (lane & 7)) * 8;  // k-half 1 slot

    for (int kk = 0; kk < 9; ++kk){
        const int dy = kk/3 - 1, dx = kk - (kk/3)*3 - 1;
        const u16* aPtr[4];
#pragma unroll
        for (int s = 0; s < 4; ++s){
            int yy = yA[s] + dy, xx = xA[s] + dx;
            bool valid = (yy >= 0) & (yy < 7) & (xx >= 0) & (xx < 7);
            aPtr[s] = valid ? in_t + (size_t)(nA[s]*49 + yy*7 + xx)*Cin + swz
                            : zpage + swz;
        }
        const size_t bko = (size_t)kk * Cin;
        for (int c0 = 0; c0 < Cin; c0 += 64){
#pragma unroll
            for (int s = 0; s < 4; ++s){
                gload16(aPtr[s] + c0, ldsA[s]);
                gload16(bRow[s] + bko + c0, ldsB[s]);
            }
            __syncthreads();   // vmcnt(0) drain + barrier: tile resident
            short8 af[4], bf[4];
#pragma unroll
            for (int i = 0; i < 4; ++i) af[i] = *(const short8*)&As[(rA0 + i*16)*64 + sl0];
#pragma unroll
            for (int j = 0; j < 4; ++j) bf[j] = *(const short8*)&Bs[(rB0 + j*16)*64 + sl0];
#pragma unroll
            for (int i = 0; i < 4; ++i)
#pragma unroll
                for (int j = 0; j < 4; ++j)
                    acc[i][j] = __builtin_amdgcn_mfma_f32_16x16x32_bf16(
                                    af[i], bf[j], acc[i][j], 0, 0, 0);
#pragma unroll
            for (int i = 0; i < 4; ++i) af[i] = *(const short8*)&As[(rA0 + i*16)*64 + sl1];
#pragma unroll
            for (int j = 0; j < 4; ++j) bf[j] = *(const short8*)&Bs[(rB0 + j*16)*64 + sl1];
#pragma unroll
            for (int i = 0; i < 4; ++i)
#pragma unroll
                for (int j = 0; j < 4; ++j)
                    acc[i][j] = __builtin_amdgcn_mfma_f32_16x16x32_bf16(
                                    af[i], bf[j], acc[i][j], 0, 0, 0);
            __syncthreads();   // protect LDS before next overwrite
        }
    }

    const int isf32 = (mode == 1) ? dtf[0] : 0;
#pragma unroll
    for (int i = 0; i < 4; ++i){
        int mbase = m0 + wm + i*16 + (lane >> 4)*4;
#pragma unroll
        for (int j = 0; j < 4; ++j){
            int co = co0 + wn + j*16 + (lane & 15);
#pragma unroll
            for (int r = 0; r < 4; ++r){
                int m = mbase + r;
                float v = acc[i][j][r];
                if (mode == 0){
                    out_cl[(size_t)(co >> 9)*((size_t)MTOT*CH)
                           + (size_t)m*CH + (co & 511)] = f2b(v);
                } else {
                    float res = b2f(feat_res[(size_t)m*CH + co]);
                    int n = m / 49, hw = m - (m/49)*49;
                    size_t off = (size_t)branch*MTOT*CH + ((size_t)n*CH + co)*HW + hw;
                    float o = v + res;
                    if (isf32) ((float*)out_base)[off] = o;
                    else       ((u16*)out_base)[off]   = f2b(o);
                }
            }
        }
    }
}

// ---------------- q conv: spatially-constant 5-ch input ----------------------
__global__ void k_qconv(const u16* __restrict__ status, const u16* __restrict__ rois,
                        const u16* __restrict__ wq, u16* __restrict__ q_t, int branch){
    const int n = blockIdx.x, hw = blockIdx.y;
    const int co = threadIdx.x;          // 512 threads
    const int y = hw / 7, x = hw - (hw/7)*7;
    float sval[5];
    sval[0] = b2f(status[n*2 + branch]);
    for (int c = 1; c < 5; ++c) sval[c] = b2f(rois[n*5 + c]);
    float acc = 0.f;
    for (int c = 0; c < 5; ++c){
        float wsum = 0.f;
        for (int ky = 0; ky < 3; ++ky){
            int yy = y + ky - 1; if (yy < 0 || yy >= 7) continue;
            for (int kx = 0; kx < 3; ++kx){
                int xx = x + kx - 1; if (xx < 0 || xx >= 7) continue;
                wsum += b2f(wq[(co*5 + c)*9 + ky*3 + kx]);
            }
        }
        acc += sval[c] * wsum;
    }
    q_t[((size_t)n*HW + hw)*CH + co] = f2b(acc);
}

// ---------------- attention per (g, hw) --------------------------------------
__global__ void k_att(const u16* __restrict__ q_t, const u16* __restrict__ k_t,
                      const u16* __restrict__ v_t, u16* __restrict__ virt_t){
    __shared__ u16 qs[16*520], ks[16*520], vs[16*520];
    __shared__ float ls[256], ps[256];
    const int hw = blockIdx.x, g = blockIdx.y;
    const int tid = threadIdx.x;
    for (int idx = tid; idx < 16*512; idx += 256){
        int i = idx >> 9, c = idx & 511;
        size_t m = (size_t)(g*16 + i)*HW + hw;
        qs[i*520 + c] = q_t[m*CH + c];
        ks[i*520 + c] = k_t[m*CH + c];
        vs[i*520 + c] = v_t[m*CH + c];
    }
    __syncthreads();
    const int i = tid >> 4, j = tid & 15;
    float dot = 0.f;
    for (int c = 0; c < 512; ++c) dot += b2f(qs[i*520 + c]) * b2f(ks[j*520 + c]);
    ls[tid] = dot * 0.04419417382415922f;   // 1/sqrt(512)
    __syncthreads();
    float mx = -1e30f;
    for (int jj = 0; jj < 16; ++jj) mx = fmaxf(mx, ls[i*16 + jj]);
    float ssum = 0.f;
    for (int jj = 0; jj < 16; ++jj) ssum += __expf(ls[i*16 + jj] - mx);
    ps[tid] = __expf(ls[tid] - mx) / ssum;
    __syncthreads();
    const int c0 = tid & 15, ii = tid >> 4;
    for (int c = c0; c < 512; c += 16){
        float a = 0.f;
        for (int jj = 0; jj < 16; ++jj) a += ps[ii*16 + jj] * b2f(vs[jj*520 + c]);
        virt_t[((size_t)(g*16 + ii)*HW + hw)*CH + c] = f2b(a);
    }
}

// ---------------- per-sample mean/rstd over 512*49 ---------------------------
__global__ void k_stats(const u16* __restrict__ virt_t, float* __restrict__ stats){
    const int n = blockIdx.x;
    const u16* p = virt_t + (size_t)n * (CH*HW);
    float s = 0.f, s2 = 0.f;
    for (int idx = threadIdx.x; idx < CH*HW; idx += 256){
        float v = b2f(p[idx]); s += v; s2 += v*v;
    }
    for (int off = 32; off; off >>= 1){
        s  += __shfl_down(s,  off, 64);
        s2 += __shfl_down(s2, off, 64);
    }
    __shared__ float bs[4], bs2[4];
    int wave = threadIdx.x >> 6, lane = threadIdx.x & 63;
    if (lane == 0){ bs[wave] = s; bs2[wave] = s2; }
    __syncthreads();
    if (threadIdx.x == 0){
        float t = 0.f, t2 = 0.f;
        for (int w = 0; w < 4; ++w){ t += bs[w]; t2 += bs2[w]; }
        float mean = t / (float)(CH*HW);
        float var  = t2 / (float)(CH*HW) - mean*mean;
        stats[n*2]   = mean;
        stats[n*2+1] = rsqrtf(var + 1e-5f);
    }
}

// ---------------- normalize + relu ------------------------------------------
__global__ void k_norm(const u16* __restrict__ virt_t, const float* __restrict__ stats,
                       const u16* __restrict__ gamma, const u16* __restrict__ beta,
                       u16* __restrict__ h_t){
    size_t idx = (size_t)blockIdx.x*256 + threadIdx.x;
    if (idx >= (size_t)NS*HW*CH) return;
    int c = (int)(idx & 511);
    int m = (int)(idx >> 9);
    int n = m / 49;
    float v = b2f(virt_t[idx]);
    float h = (v - stats[n*2]) * stats[n*2+1] * b2f(gamma[c]) + b2f(beta[c]);
    h_t[idx] = f2b(fmaxf(h, 0.f));
}

extern "C" void kernel_launch(void* const* d_in, const int* in_sizes, int n_in,
                              void* d_out, int out_size, void* d_ws, size_t ws_size,
                              hipStream_t stream) {
    const void* status   = d_in[0];
    const void* rois     = d_in[1];
    const void* bbox     = d_in[2];
    const void* w_reduce = d_in[3];
    const void* w_q1     = d_in[4];
    const void* w_q2     = d_in[5];
    const void* w_k1     = d_in[6];
    const void* w_v1     = d_in[7];
    const void* w_k2     = d_in[8];
    const void* w_v2     = d_in[9];
    const void* w_c1     = d_in[10];
    const void* w_c2     = d_in[11];
    const void* gamma    = d_in[12];
    const void* beta     = d_in[13];

    // ---- workspace layout with aliasing (total ~120.4 MB) ----
    char* p = (char*)d_ws;
    const size_t SZ_INT  = (size_t)MTOT*CIN*2;   // 57,802,752  region0
    const size_t SZ_WRT  = (size_t)CH*9*CIN*2;   // 21,233,664  region1
    const size_t SZ_T    = (size_t)MTOT*CH*2;    // 12,845,056
    const size_t SZ_WT   = (size_t)CH*9*CH*2;    //  4,718,592

    u16* in_t  = (u16*)p;
    u16* w_r_t = (u16*)(p + SZ_INT);
    char* p2   = p + SZ_INT + SZ_WRT;
    u16* wt[6];
    for (int i = 0; i < 6; ++i) wt[i] = (u16*)(p2 + i*SZ_WT);
    u16* feat_t = (u16*)(p2 + 6*SZ_WT);
    char* p3 = p2 + 6*SZ_WT + SZ_T;
    float* stats    = (float*)p3;
    int*   flag     = (int*)(p3 + 4096);
    u16*   status_c = (u16*)(p3 + 8192);
    u16*   rois_c   = status_c + 1024;
    u16*   gamma_c  = rois_c + 2048;
    u16*   beta_c   = gamma_c + 512;
    u16*   wq_c0    = beta_c + 512;
    u16*   wq_c1    = wq_c0 + CH*5*9;
    u16*   zp       = wq_c1 + CH*5*9;     // 8 KB zero page for padding taps
    // aliases into regions dead after the feat conv:
    u16* q_t    = (u16*)p;
    u16* k_t    = (u16*)(p + SZ_T);
    u16* v_t    = (u16*)(p + 2*SZ_T);   // contiguous after k_t (KV-fused writes)
    u16* virt_t = (u16*)(p + 3*SZ_T);   // 4*SZ_T = 51.4MB <= 57.8MB
    u16* h_t    = w_r_t;                // 12.85MB <= 21.2MB

    k_detect<<<1, 256, 0, stream>>>((const u16*)bbox, flag);
    k_zero<<<16, 256, 0, stream>>>(zp, 4096);
    k_transpose_in<<<dim3(NS, CIN/64), 256, 0, stream>>>(bbox, in_t, flag);
    k_transpose_w<<<1024, 256, 0, stream>>>(w_reduce, w_r_t, CIN, flag);
    const void* wsrc[6] = {w_k1, w_v1, w_k2, w_v2, w_c1, w_c2};
    for (int i = 0; i < 6; ++i)
        k_transpose_w<<<512, 256, 0, stream>>>(wsrc[i], wt[i], CH, flag);
    k_convert_small<<<2, 256, 0, stream>>>(status, status_c, NS*2, flag);
    k_convert_small<<<5, 256, 0, stream>>>(rois, rois_c, NS*5, flag);
    k_convert_small<<<2, 256, 0, stream>>>(gamma, gamma_c, CH, flag);
    k_convert_small<<<2, 256, 0, stream>>>(beta, beta_c, CH, flag);
    k_convert_small<<<90, 256, 0, stream>>>(w_q1, wq_c0, CH*5*9, flag);
    k_convert_small<<<90, 256, 0, stream>>>(w_q2, wq_c1, CH*5*9, flag);

    // reduce conv: M=12544, N=512, K=9*2304
    k_conv3x3<<<dim3(MTOT/128, CH/128), 256, 0, stream>>>(
        in_t, w_r_t, CIN, zp, feat_t, nullptr, nullptr, 0, 0, flag);

    for (int br = 0; br < 2; ++br){
        k_qconv<<<dim3(NS, HW), 512, 0, stream>>>(status_c, rois_c,
                                                  br ? wq_c1 : wq_c0, q_t, br);
        // fused K+V conv: N=1024 (wt[br*2],wt[br*2+1] contiguous), writes k_t|v_t
        k_conv3x3<<<dim3(MTOT/128, 1024/128), 256, 0, stream>>>(
            feat_t, wt[br*2], CH, zp, k_t, nullptr, nullptr, 0, 0, flag);
        k_att<<<dim3(HW, 16), 256, 0, stream>>>(q_t, k_t, v_t, virt_t);
        k_stats<<<NS, 256, 0, stream>>>(virt_t, stats);
        k_norm<<<(NS*HW*CH)/256, 256, 0, stream>>>(virt_t, stats, gamma_c, beta_c, h_t);
        k_conv3x3<<<dim3(MTOT/128, CH/128), 256, 0, stream>>>(
            h_t, wt[4 + br], CH, zp, nullptr, feat_t, d_out, 1, br, flag);
    }
}

// Round 2
// 1945.202 us; speedup vs baseline: 4.3017x; 1.0668x over previous
//
#include <hip/hip_runtime.h>
#include <stdint.h>

typedef unsigned short u16;
typedef short short8 __attribute__((ext_vector_type(8)));
typedef float f32x4 __attribute__((ext_vector_type(4)));

#define NS 256
#define CIN 2304
#define CH 512
#define HW 49
#define MTOT (NS*HW)   // 12544

__device__ __forceinline__ float b2f(u16 u){
    union { unsigned int v; float f; } x; x.v = ((unsigned int)u) << 16; return x.f;
}
__device__ __forceinline__ u16 f2b(float f){
    unsigned int u = __builtin_bit_cast(unsigned int, f);
    u += 0x7FFFu + ((u >> 16) & 1u);
    return (u16)(u >> 16);
}
__device__ __forceinline__ u16 load_as_bf16(const void* p, size_t i, int isf32){
    return isf32 ? f2b(((const float*)p)[i]) : ((const u16*)p)[i];
}

// async global->LDS, 16B per lane. Dest is wave-uniform base + lane*16 (HW rule).
__device__ __forceinline__ void gload16(const u16* g, u16* l){
    __builtin_amdgcn_global_load_lds((const __attribute__((address_space(1))) void*)g,
                                     (__attribute__((address_space(3))) void*)l,
                                     16, 0, 0);
}

// ---------------- dtype detector: fp32 mantissa halves have big exponents ----
__global__ void k_detect(const u16* __restrict__ src, int* __restrict__ flag){
    int cnt = 0;
    for (int i = threadIdx.x; i < 8192; i += 256){
        int e = (src[i] >> 7) & 0xFF;
        cnt += (e >= 0x90);
    }
    for (int off = 32; off; off >>= 1) cnt += __shfl_down(cnt, off, 64);
    __shared__ int sh[4];
    int wave = threadIdx.x >> 6, lane = threadIdx.x & 63;
    if (lane == 0) sh[wave] = cnt;
    __syncthreads();
    if (threadIdx.x == 0)
        flag[0] = (sh[0] + sh[1] + sh[2] + sh[3] > 200) ? 1 : 0;
}

// ---------------- zero filler ------------------------------------------------
__global__ void k_zero(u16* __restrict__ p, int n){
    int i = blockIdx.x*256 + threadIdx.x;
    if (i < n) p[i] = 0;
}

// ---------------- small converter (to bf16) ----------------------------------
__global__ void k_convert_small(const void* __restrict__ src, u16* __restrict__ dst,
                                int n, const int* __restrict__ flag){
    const int isf32 = flag[0];
    for (int i = blockIdx.x*256 + threadIdx.x; i < n; i += gridDim.x*256)
        dst[i] = load_as_bf16(src, i, isf32);
}

// ---------------- transpose bbox_feat [n][2304][49] -> in_t [n][49][2304] ----
__global__ void k_transpose_in(const void* __restrict__ src, u16* __restrict__ dst,
                               const int* __restrict__ flag){
    const int isf32 = flag[0];
    __shared__ u16 tile[64*50];
    const int n = blockIdx.x;
    const int c0 = blockIdx.y * 64;
    const size_t sbase = ((size_t)n*CIN + c0)*HW;
    for (int idx = threadIdx.x; idx < 64*49; idx += 256){
        int cc = idx / 49, hw = idx - cc*49;
        tile[cc*50 + hw] = load_as_bf16(src, sbase + cc*HW + hw, isf32);
    }
    __syncthreads();
    u16* d = dst + (size_t)n*HW*CIN + c0;
    for (int idx = threadIdx.x; idx < 49*64; idx += 256){
        int hw = idx >> 6, cc = idx & 63;
        d[(size_t)hw*CIN + cc] = tile[cc*50 + hw];
    }
}

// ---------------- weight transpose [512][Cin][9] -> [512][9][Cin] ------------
__global__ void k_transpose_w(const void* __restrict__ w, u16* __restrict__ wt,
                              int Cin, const int* __restrict__ flag){
    const int isf32 = flag[0];
    size_t total = (size_t)CH * Cin * 9;
    for (size_t d = (size_t)blockIdx.x*blockDim.x + threadIdx.x; d < total;
         d += (size_t)gridDim.x*blockDim.x){
        int c  = (int)(d % Cin);
        size_t t = d / Cin;
        int kk = (int)(t % 9);
        int co = (int)(t / 9);
        wt[d] = load_as_bf16(w, ((size_t)co*Cin + c)*9 + kk, isf32);
    }
}

// ---------------- 3x3 pad-1 conv: implicit GEMM, 2-phase double-buffered -----
// Tile 128x128, BK=64, 4 waves (2x2), 4x4 16x16x32 frags per wave.
// Per K-step: STAGE(next buf via global_load_lds, XOR-swizzled source) ->
// COMPUTE(cur buf) -> __syncthreads() (vmcnt(0) drain overlapped with compute).
// Static buffer names (As0/As1) so alias analysis can't serialize the pipeline.
// mode 0: out_cl[(co>>9)*MTOT*CH + m*CH + (co&511)] = acc   (N=1024 KV fusion)
// mode 1: out[branch][n][co][hw] = acc + feat_res[m][co], dtype per dtf
__global__ __launch_bounds__(256, 2) void k_conv3x3(
        const u16* __restrict__ in_t, const u16* __restrict__ w_t, int Cin,
        const u16* __restrict__ zpage,
        u16* __restrict__ out_cl,
        const u16* __restrict__ feat_res, void* __restrict__ out_base,
        int mode, int branch, const int* __restrict__ dtf)
{
    __shared__ __align__(16) u16 As0[128*64];
    __shared__ __align__(16) u16 Bs0[128*64];
    __shared__ __align__(16) u16 As1[128*64];
    __shared__ __align__(16) u16 Bs1[128*64];
    const int tid  = threadIdx.x;
    const int wave = tid >> 6, lane = tid & 63;
    const int m0  = blockIdx.x * 128;
    const int co0 = blockIdx.y * 128;

    // ---- loader mapping: thread t covers LDS rows (t>>3)+32s, 16B slot t&7 ----
    const int lr  = tid >> 3;                 // 0..31
    const int sl  = tid & 7;                  // 16B slot within 128B row
    const int swz = (sl ^ (lr & 7)) * 8;      // pre-swizzled source elem offset

    int nA[4], yA[4], xA[4];
#pragma unroll
    for (int s = 0; s < 4; ++s){
        int m = m0 + lr + 32*s;
        nA[s] = m / 49;
        int hw = m - nA[s]*49;
        yA[s] = hw / 7; xA[s] = hw - yA[s]*7;
    }

    // ---- staging state: walks the flattened K dimension (9 taps x Cin) ------
    const u16* aPtr[4];
    const u16* bPtr[4];
#pragma unroll
    for (int s = 0; s < 4; ++s)
        bPtr[s] = w_t + (size_t)(co0 + lr + 32*s)*9*Cin + swz;
    int kkS = 0, c0S = 0;

    auto recompTaps = [&](){
        int dy = kkS/3 - 1, dx = kkS - (kkS/3)*3 - 1;
#pragma unroll
        for (int s = 0; s < 4; ++s){
            int yy = yA[s] + dy, xx = xA[s] + dx;
            bool valid = (yy >= 0) & (yy < 7) & (xx >= 0) & (xx < 7);
            aPtr[s] = valid ? in_t + (size_t)(nA[s]*49 + yy*7 + xx)*Cin + swz
                            : zpage + swz;
        }
    };
    recompTaps();

    int dstOff[4];
#pragma unroll
    for (int s = 0; s < 4; ++s) dstOff[s] = (wave*8 + s*32)*64;

    auto STAGE = [&](u16* A, u16* B){
#pragma unroll
        for (int s = 0; s < 4; ++s){
            gload16(aPtr[s], A + dstOff[s]);
            gload16(bPtr[s], B + dstOff[s]);
        }
    };
    auto ADV = [&](){
#pragma unroll
        for (int s = 0; s < 4; ++s){ aPtr[s] += 64; bPtr[s] += 64; }
        c0S += 64;
        if (c0S == Cin){
            c0S = 0; ++kkS;
            if (kkS < 9) recompTaps();
        }
    };

    f32x4 acc[4][4];
#pragma unroll
    for (int i = 0; i < 4; ++i)
#pragma unroll
        for (int j = 0; j < 4; ++j)
            acc[i][j] = (f32x4){0.f, 0.f, 0.f, 0.f};

    const int wm = (wave & 1) * 64, wn = (wave >> 1) * 64;
    const int rA0 = wm + (lane & 15);
    const int rB0 = wn + (lane & 15);
    const int sl0 = (((lane >> 4)    ) ^ (lane & 7)) * 8;  // k-half 0 slot (elems)
    const int sl1 = ((4 + (lane >> 4)) ^ (lane & 7)) * 8;  // k-half 1 slot

    auto COMPUTE = [&](const u16* A, const u16* B){
        short8 af[4], bf[4];
#pragma unroll
        for (int i = 0; i < 4; ++i) af[i] = *(const short8*)&A[(rA0 + i*16)*64 + sl0];
#pragma unroll
        for (int j = 0; j < 4; ++j) bf[j] = *(const short8*)&B[(rB0 + j*16)*64 + sl0];
#pragma unroll
        for (int i = 0; i < 4; ++i)
#pragma unroll
            for (int j = 0; j < 4; ++j)
                acc[i][j] = __builtin_amdgcn_mfma_f32_16x16x32_bf16(
                                af[i], bf[j], acc[i][j], 0, 0, 0);
#pragma unroll
        for (int i = 0; i < 4; ++i) af[i] = *(const short8*)&A[(rA0 + i*16)*64 + sl1];
#pragma unroll
        for (int j = 0; j < 4; ++j) bf[j] = *(const short8*)&B[(rB0 + j*16)*64 + sl1];
#pragma unroll
        for (int i = 0; i < 4; ++i)
#pragma unroll
            for (int j = 0; j < 4; ++j)
                acc[i][j] = __builtin_amdgcn_mfma_f32_16x16x32_bf16(
                                af[i], bf[j], acc[i][j], 0, 0, 0);
    };

    // ---- pipeline: stage(t) | compute(t-1) overlapped; one barrier per step --
    const int NK = 9 * (Cin >> 6);   // 324 (Cin=2304) or 72 (Cin=512), even
    STAGE(As0, Bs0); ADV();
    __syncthreads();                 // cold drain, once
    for (int t = 0; t < NK; t += 2){
        STAGE(As1, Bs1); ADV();      // step t+1 in flight
        COMPUTE(As0, Bs0);           // step t
        __syncthreads();             // drains As1/Bs1 loads (hidden under compute)
        if (t + 2 < NK){ STAGE(As0, Bs0); ADV(); }
        COMPUTE(As1, Bs1);           // step t+1
        __syncthreads();
    }

    const int isf32 = (mode == 1) ? dtf[0] : 0;
#pragma unroll
    for (int i = 0; i < 4; ++i){
        int mbase = m0 + wm + i*16 + (lane >> 4)*4;
#pragma unroll
        for (int j = 0; j < 4; ++j){
            int co = co0 + wn + j*16 + (lane & 15);
#pragma unroll
            for (int r = 0; r < 4; ++r){
                int m = mbase + r;
                float v = acc[i][j][r];
                if (mode == 0){
                    out_cl[(size_t)(co >> 9)*((size_t)MTOT*CH)
                           + (size_t)m*CH + (co & 511)] = f2b(v);
                } else {
                    float res = b2f(feat_res[(size_t)m*CH + co]);
                    int n = m / 49, hw = m - (m/49)*49;
                    size_t off = (size_t)branch*MTOT*CH + ((size_t)n*CH + co)*HW + hw;
                    float o = v + res;
                    if (isf32) ((float*)out_base)[off] = o;
                    else       ((u16*)out_base)[off]   = f2b(o);
                }
            }
        }
    }
}

// ---------------- q conv: spatially-constant 5-ch input ----------------------
__global__ void k_qconv(const u16* __restrict__ status, const u16* __restrict__ rois,
                        const u16* __restrict__ wq, u16* __restrict__ q_t, int branch){
    const int n = blockIdx.x, hw = blockIdx.y;
    const int co = threadIdx.x;          // 512 threads
    const int y = hw / 7, x = hw - (hw/7)*7;
    float sval[5];
    sval[0] = b2f(status[n*2 + branch]);
    for (int c = 1; c < 5; ++c) sval[c] = b2f(rois[n*5 + c]);
    float acc = 0.f;
    for (int c = 0; c < 5; ++c){
        float wsum = 0.f;
        for (int ky = 0; ky < 3; ++ky){
            int yy = y + ky - 1; if (yy < 0 || yy >= 7) continue;
            for (int kx = 0; kx < 3; ++kx){
                int xx = x + kx - 1; if (xx < 0 || xx >= 7) continue;
                wsum += b2f(wq[(co*5 + c)*9 + ky*3 + kx]);
            }
        }
        acc += sval[c] * wsum;
    }
    q_t[((size_t)n*HW + hw)*CH + co] = f2b(acc);
}

// ---------------- attention per (g, hw) --------------------------------------
__global__ void k_att(const u16* __restrict__ q_t, const u16* __restrict__ k_t,
                      const u16* __restrict__ v_t, u16* __restrict__ virt_t){
    __shared__ u16 qs[16*520], ks[16*520], vs[16*520];
    __shared__ float ls[256], ps[256];
    const int hw = blockIdx.x, g = blockIdx.y;
    const int tid = threadIdx.x;
    for (int idx = tid; idx < 16*512; idx += 256){
        int i = idx >> 9, c = idx & 511;
        size_t m = (size_t)(g*16 + i)*HW + hw;
        qs[i*520 + c] = q_t[m*CH + c];
        ks[i*520 + c] = k_t[m*CH + c];
        vs[i*520 + c] = v_t[m*CH + c];
    }
    __syncthreads();
    const int i = tid >> 4, j = tid & 15;
    float dot = 0.f;
    for (int c = 0; c < 512; ++c) dot += b2f(qs[i*520 + c]) * b2f(ks[j*520 + c]);
    ls[tid] = dot * 0.04419417382415922f;   // 1/sqrt(512)
    __syncthreads();
    float mx = -1e30f;
    for (int jj = 0; jj < 16; ++jj) mx = fmaxf(mx, ls[i*16 + jj]);
    float ssum = 0.f;
    for (int jj = 0; jj < 16; ++jj) ssum += __expf(ls[i*16 + jj] - mx);
    ps[tid] = __expf(ls[tid] - mx) / ssum;
    __syncthreads();
    const int c0 = tid & 15, ii = tid >> 4;
    for (int c = c0; c < 512; c += 16){
        float a = 0.f;
        for (int jj = 0; jj < 16; ++jj) a += ps[ii*16 + jj] * b2f(vs[jj*520 + c]);
        virt_t[((size_t)(g*16 + ii)*HW + hw)*CH + c] = f2b(a);
    }
}

// ---------------- per-sample mean/rstd over 512*49 ---------------------------
__global__ void k_stats(const u16* __restrict__ virt_t, float* __restrict__ stats){
    const int n = blockIdx.x;
    const u16* p = virt_t + (size_t)n * (CH*HW);
    float s = 0.f, s2 = 0.f;
    for (int idx = threadIdx.x; idx < CH*HW; idx += 256){
        float v = b2f(p[idx]); s += v; s2 += v*v;
    }
    for (int off = 32; off; off >>= 1){
        s  += __shfl_down(s,  off, 64);
        s2 += __shfl_down(s2, off, 64);
    }
    __shared__ float bs[4], bs2[4];
    int wave = threadIdx.x >> 6, lane = threadIdx.x & 63;
    if (lane == 0){ bs[wave] = s; bs2[wave] = s2; }
    __syncthreads();
    if (threadIdx.x == 0){
        float t = 0.f, t2 = 0.f;
        for (int w = 0; w < 4; ++w){ t += bs[w]; t2 += bs2[w]; }
        float mean = t / (float)(CH*HW);
        float var  = t2 / (float)(CH*HW) - mean*mean;
        stats[n*2]   = mean;
        stats[n*2+1] = rsqrtf(var + 1e-5f);
    }
}

// ---------------- normalize + relu ------------------------------------------
__global__ void k_norm(const u16* __restrict__ virt_t, const float* __restrict__ stats,
                       const u16* __restrict__ gamma, const u16* __restrict__ beta,
                       u16* __restrict__ h_t){
    size_t idx = (size_t)blockIdx.x*256 + threadIdx.x;
    if (idx >= (size_t)NS*HW*CH) return;
    int c = (int)(idx & 511);
    int m = (int)(idx >> 9);
    int n = m / 49;
    float v = b2f(virt_t[idx]);
    float h = (v - stats[n*2]) * stats[n*2+1] * b2f(gamma[c]) + b2f(beta[c]);
    h_t[idx] = f2b(fmaxf(h, 0.f));
}

extern "C" void kernel_launch(void* const* d_in, const int* in_sizes, int n_in,
                              void* d_out, int out_size, void* d_ws, size_t ws_size,
                              hipStream_t stream) {
    const void* status   = d_in[0];
    const void* rois     = d_in[1];
    const void* bbox     = d_in[2];
    const void* w_reduce = d_in[3];
    const void* w_q1     = d_in[4];
    const void* w_q2     = d_in[5];
    const void* w_k1     = d_in[6];
    const void* w_v1     = d_in[7];
    const void* w_k2     = d_in[8];
    const void* w_v2     = d_in[9];
    const void* w_c1     = d_in[10];
    const void* w_c2     = d_in[11];
    const void* gamma    = d_in[12];
    const void* beta     = d_in[13];

    // ---- workspace layout with aliasing (total ~120.4 MB) ----
    char* p = (char*)d_ws;
    const size_t SZ_INT  = (size_t)MTOT*CIN*2;   // 57,802,752  region0
    const size_t SZ_WRT  = (size_t)CH*9*CIN*2;   // 21,233,664  region1
    const size_t SZ_T    = (size_t)MTOT*CH*2;    // 12,845,056
    const size_t SZ_WT   = (size_t)CH*9*CH*2;    //  4,718,592

    u16* in_t  = (u16*)p;
    u16* w_r_t = (u16*)(p + SZ_INT);
    char* p2   = p + SZ_INT + SZ_WRT;
    u16* wt[6];
    for (int i = 0; i < 6; ++i) wt[i] = (u16*)(p2 + i*SZ_WT);
    u16* feat_t = (u16*)(p2 + 6*SZ_WT);
    char* p3 = p2 + 6*SZ_WT + SZ_T;
    float* stats    = (float*)p3;
    int*   flag     = (int*)(p3 + 4096);
    u16*   status_c = (u16*)(p3 + 8192);
    u16*   rois_c   = status_c + 1024;
    u16*   gamma_c  = rois_c + 2048;
    u16*   beta_c   = gamma_c + 512;
    u16*   wq_c0    = beta_c + 512;
    u16*   wq_c1    = wq_c0 + CH*5*9;
    u16*   zp       = wq_c1 + CH*5*9;     // 8 KB zero page for padding taps
    // aliases into regions dead after the feat conv:
    u16* q_t    = (u16*)p;
    u16* k_t    = (u16*)(p + SZ_T);
    u16* v_t    = (u16*)(p + 2*SZ_T);   // contiguous after k_t (KV-fused writes)
    u16* virt_t = (u16*)(p + 3*SZ_T);   // 4*SZ_T = 51.4MB <= 57.8MB
    u16* h_t    = w_r_t;                // 12.85MB <= 21.2MB

    k_detect<<<1, 256, 0, stream>>>((const u16*)bbox, flag);
    k_zero<<<16, 256, 0, stream>>>(zp, 4096);
    k_transpose_in<<<dim3(NS, CIN/64), 256, 0, stream>>>(bbox, in_t, flag);
    k_transpose_w<<<1024, 256, 0, stream>>>(w_reduce, w_r_t, CIN, flag);
    const void* wsrc[6] = {w_k1, w_v1, w_k2, w_v2, w_c1, w_c2};
    for (int i = 0; i < 6; ++i)
        k_transpose_w<<<512, 256, 0, stream>>>(wsrc[i], wt[i], CH, flag);
    k_convert_small<<<2, 256, 0, stream>>>(status, status_c, NS*2, flag);
    k_convert_small<<<5, 256, 0, stream>>>(rois, rois_c, NS*5, flag);
    k_convert_small<<<2, 256, 0, stream>>>(gamma, gamma_c, CH, flag);
    k_convert_small<<<2, 256, 0, stream>>>(beta, beta_c, CH, flag);
    k_convert_small<<<90, 256, 0, stream>>>(w_q1, wq_c0, CH*5*9, flag);
    k_convert_small<<<90, 256, 0, stream>>>(w_q2, wq_c1, CH*5*9, flag);

    // reduce conv: M=12544, N=512, K=9*2304
    k_conv3x3<<<dim3(MTOT/128, CH/128), 256, 0, stream>>>(
        in_t, w_r_t, CIN, zp, feat_t, nullptr, nullptr, 0, 0, flag);

    for (int br = 0; br < 2; ++br){
        k_qconv<<<dim3(NS, HW), 512, 0, stream>>>(status_c, rois_c,
                                                  br ? wq_c1 : wq_c0, q_t, br);
        // fused K+V conv: N=1024 (wt[br*2],wt[br*2+1] contiguous), writes k_t|v_t
        k_conv3x3<<<dim3(MTOT/128, 1024/128), 256, 0, stream>>>(
            feat_t, wt[br*2], CH, zp, k_t, nullptr, nullptr, 0, 0, flag);
        k_att<<<dim3(HW, 16), 256, 0, stream>>>(q_t, k_t, v_t, virt_t);
        k_stats<<<NS, 256, 0, stream>>>(virt_t, stats);
        k_norm<<<(NS*HW*CH)/256, 256, 0, stream>>>(virt_t, stats, gamma_c, beta_c, h_t);
        k_conv3x3<<<dim3(MTOT/128, CH/128), 256, 0, stream>>>(
            h_t, wt[4 + br], CH, zp, nullptr, feat_t, d_out, 1, br, flag);
    }
}

// Round 3
// 1339.609 us; speedup vs baseline: 6.2463x; 1.4521x over previous
//
#include <hip/hip_runtime.h>
#include <stdint.h>

typedef unsigned short u16;
typedef short short8 __attribute__((ext_vector_type(8)));
typedef float f32x4 __attribute__((ext_vector_type(4)));

#define NS 256
#define CIN 2304
#define CH 512
#define HW 49
#define MTOT (NS*HW)   // 12544

__device__ __forceinline__ float b2f(u16 u){
    union { unsigned int v; float f; } x; x.v = ((unsigned int)u) << 16; return x.f;
}
__device__ __forceinline__ u16 f2b(float f){
    unsigned int u = __builtin_bit_cast(unsigned int, f);
    u += 0x7FFFu + ((u >> 16) & 1u);
    return (u16)(u >> 16);
}
__device__ __forceinline__ u16 load_as_bf16(const void* p, size_t i, int isf32){
    return isf32 ? f2b(((const float*)p)[i]) : ((const u16*)p)[i];
}

// async global->LDS, 16B per lane. Dest is wave-uniform base + lane*16 (HW rule).
__device__ __forceinline__ void gload16(const u16* g, u16* l){
    __builtin_amdgcn_global_load_lds((const __attribute__((address_space(1))) void*)g,
                                     (__attribute__((address_space(3))) void*)l,
                                     16, 0, 0);
}

// ---------------- dtype detector: fp32 mantissa halves have big exponents ----
__global__ void k_detect(const u16* __restrict__ src, int* __restrict__ flag){
    int cnt = 0;
    for (int i = threadIdx.x; i < 8192; i += 256){
        int e = (src[i] >> 7) & 0xFF;
        cnt += (e >= 0x90);
    }
    for (int off = 32; off; off >>= 1) cnt += __shfl_down(cnt, off, 64);
    __shared__ int sh[4];
    int wave = threadIdx.x >> 6, lane = threadIdx.x & 63;
    if (lane == 0) sh[wave] = cnt;
    __syncthreads();
    if (threadIdx.x == 0)
        flag[0] = (sh[0] + sh[1] + sh[2] + sh[3] > 200) ? 1 : 0;
}

// ---------------- zero filler ------------------------------------------------
__global__ void k_zero(u16* __restrict__ p, int n){
    int i = blockIdx.x*256 + threadIdx.x;
    if (i < n) p[i] = 0;
}

// ---------------- small converter (to bf16) ----------------------------------
__global__ void k_convert_small(const void* __restrict__ src, u16* __restrict__ dst,
                                int n, const int* __restrict__ flag){
    const int isf32 = flag[0];
    for (int i = blockIdx.x*256 + threadIdx.x; i < n; i += gridDim.x*256)
        dst[i] = load_as_bf16(src, i, isf32);
}

// ---------------- transpose bbox_feat [n][2304][49] -> in_t [n][49][2304] ----
__global__ void k_transpose_in(const void* __restrict__ src, u16* __restrict__ dst,
                               const int* __restrict__ flag){
    const int isf32 = flag[0];
    __shared__ u16 tile[64*50];
    const int n = blockIdx.x;
    const int c0 = blockIdx.y * 64;
    const size_t sbase = ((size_t)n*CIN + c0)*HW;
    for (int idx = threadIdx.x; idx < 64*49; idx += 256){
        int cc = idx / 49, hw = idx - cc*49;
        tile[cc*50 + hw] = load_as_bf16(src, sbase + cc*HW + hw, isf32);
    }
    __syncthreads();
    u16* d = dst + (size_t)n*HW*CIN + c0;
    for (int idx = threadIdx.x; idx < 49*64; idx += 256){
        int hw = idx >> 6, cc = idx & 63;
        d[(size_t)hw*CIN + cc] = tile[cc*50 + hw];
    }
}

// ---------------- weight transpose [512][Cin][9] -> [512][9][Cin] ------------
__global__ void k_transpose_w(const void* __restrict__ w, u16* __restrict__ wt,
                              int Cin, const int* __restrict__ flag){
    const int isf32 = flag[0];
    size_t total = (size_t)CH * Cin * 9;
    for (size_t d = (size_t)blockIdx.x*blockDim.x + threadIdx.x; d < total;
         d += (size_t)gridDim.x*blockDim.x){
        int c  = (int)(d % Cin);
        size_t t = d / Cin;
        int kk = (int)(t % 9);
        int co = (int)(t / 9);
        wt[d] = load_as_bf16(w, ((size_t)co*Cin + c)*9 + kk, isf32);
    }
}

// ---------------- 3x3 pad-1 conv: implicit GEMM, 2-phase double-buffered -----
// Tile 128x128, BK=64, 4 waves (2x2), 4x4 16x16x32 frags per wave.
// Per K-step: STAGE(next buf via global_load_lds, XOR-swizzled source) ->
// COMPUTE(cur buf) -> __syncthreads() (vmcnt(0) drain overlapped with compute).
// Static buffer names (As0/As1) so alias analysis can't serialize the pipeline.
// mode 0: out_cl[(co>>9)*MTOT*CH + m*CH + (co&511)] = acc   (N=1024 KV fusion)
// mode 1: out[branch][n][co][hw] = acc + feat_res[m][co], dtype per dtf
__global__ __launch_bounds__(256, 2) void k_conv3x3(
        const u16* __restrict__ in_t, const u16* __restrict__ w_t, int Cin,
        const u16* __restrict__ zpage,
        u16* __restrict__ out_cl,
        const u16* __restrict__ feat_res, void* __restrict__ out_base,
        int mode, int branch, const int* __restrict__ dtf)
{
    __shared__ __align__(16) u16 As0[128*64];
    __shared__ __align__(16) u16 Bs0[128*64];
    __shared__ __align__(16) u16 As1[128*64];
    __shared__ __align__(16) u16 Bs1[128*64];
    const int tid  = threadIdx.x;
    const int wave = tid >> 6, lane = tid & 63;
    const int m0  = blockIdx.x * 128;
    const int co0 = blockIdx.y * 128;

    // ---- loader mapping: thread t covers LDS rows (t>>3)+32s, 16B slot t&7 ----
    const int lr  = tid >> 3;                 // 0..31
    const int sl  = tid & 7;                  // 16B slot within 128B row
    const int swz = (sl ^ (lr & 7)) * 8;      // pre-swizzled source elem offset

    int nA[4], yA[4], xA[4];
#pragma unroll
    for (int s = 0; s < 4; ++s){
        int m = m0 + lr + 32*s;
        nA[s] = m / 49;
        int hw = m - nA[s]*49;
        yA[s] = hw / 7; xA[s] = hw - yA[s]*7;
    }

    // ---- staging state: walks the flattened K dimension (9 taps x Cin) ------
    const u16* aPtr[4];
    const u16* bPtr[4];
#pragma unroll
    for (int s = 0; s < 4; ++s)
        bPtr[s] = w_t + (size_t)(co0 + lr + 32*s)*9*Cin + swz;
    int kkS = 0, c0S = 0;

    auto recompTaps = [&](){
        int dy = kkS/3 - 1, dx = kkS - (kkS/3)*3 - 1;
#pragma unroll
        for (int s = 0; s < 4; ++s){
            int yy = yA[s] + dy, xx = xA[s] + dx;
            bool valid = (yy >= 0) & (yy < 7) & (xx >= 0) & (xx < 7);
            aPtr[s] = valid ? in_t + (size_t)(nA[s]*49 + yy*7 + xx)*Cin + swz
                            : zpage + swz;
        }
    };
    recompTaps();

    int dstOff[4];
#pragma unroll
    for (int s = 0; s < 4; ++s) dstOff[s] = (wave*8 + s*32)*64;

    auto STAGE = [&](u16* A, u16* B){
#pragma unroll
        for (int s = 0; s < 4; ++s){
            gload16(aPtr[s], A + dstOff[s]);
            gload16(bPtr[s], B + dstOff[s]);
        }
    };
    auto ADV = [&](){
#pragma unroll
        for (int s = 0; s < 4; ++s){ aPtr[s] += 64; bPtr[s] += 64; }
        c0S += 64;
        if (c0S == Cin){
            c0S = 0; ++kkS;
            if (kkS < 9) recompTaps();
        }
    };

    f32x4 acc[4][4];
#pragma unroll
    for (int i = 0; i < 4; ++i)
#pragma unroll
        for (int j = 0; j < 4; ++j)
            acc[i][j] = (f32x4){0.f, 0.f, 0.f, 0.f};

    const int wm = (wave & 1) * 64, wn = (wave >> 1) * 64;
    const int rA0 = wm + (lane & 15);
    const int rB0 = wn + (lane & 15);
    const int sl0 = (((lane >> 4)    ) ^ (lane & 7)) * 8;  // k-half 0 slot (elems)
    const int sl1 = ((4 + (lane >> 4)) ^ (lane & 7)) * 8;  // k-half 1 slot

    auto COMPUTE = [&](const u16* A, const u16* B){
        short8 af[4], bf[4];
#pragma unroll
        for (int i = 0; i < 4; ++i) af[i] = *(const short8*)&A[(rA0 + i*16)*64 + sl0];
#pragma unroll
        for (int j = 0; j < 4; ++j) bf[j] = *(const short8*)&B[(rB0 + j*16)*64 + sl0];
#pragma unroll
        for (int i = 0; i < 4; ++i)
#pragma unroll
            for (int j = 0; j < 4; ++j)
                acc[i][j] = __builtin_amdgcn_mfma_f32_16x16x32_bf16(
                                af[i], bf[j], acc[i][j], 0, 0, 0);
#pragma unroll
        for (int i = 0; i < 4; ++i) af[i] = *(const short8*)&A[(rA0 + i*16)*64 + sl1];
#pragma unroll
        for (int j = 0; j < 4; ++j) bf[j] = *(const short8*)&B[(rB0 + j*16)*64 + sl1];
#pragma unroll
        for (int i = 0; i < 4; ++i)
#pragma unroll
            for (int j = 0; j < 4; ++j)
                acc[i][j] = __builtin_amdgcn_mfma_f32_16x16x32_bf16(
                                af[i], bf[j], acc[i][j], 0, 0, 0);
    };

    // ---- pipeline: stage(t) | compute(t-1) overlapped; one barrier per step --
    const int NK = 9 * (Cin >> 6);   // 324 (Cin=2304) or 72 (Cin=512), even
    STAGE(As0, Bs0); ADV();
    __syncthreads();                 // cold drain, once
    for (int t = 0; t < NK; t += 2){
        STAGE(As1, Bs1); ADV();      // step t+1 in flight
        COMPUTE(As0, Bs0);           // step t
        __syncthreads();             // drains As1/Bs1 loads (hidden under compute)
        if (t + 2 < NK){ STAGE(As0, Bs0); ADV(); }
        COMPUTE(As1, Bs1);           // step t+1
        __syncthreads();
    }

    const int isf32 = (mode == 1) ? dtf[0] : 0;
#pragma unroll
    for (int i = 0; i < 4; ++i){
        int mbase = m0 + wm + i*16 + (lane >> 4)*4;
#pragma unroll
        for (int j = 0; j < 4; ++j){
            int co = co0 + wn + j*16 + (lane & 15);
#pragma unroll
            for (int r = 0; r < 4; ++r){
                int m = mbase + r;
                float v = acc[i][j][r];
                if (mode == 0){
                    out_cl[(size_t)(co >> 9)*((size_t)MTOT*CH)
                           + (size_t)m*CH + (co & 511)] = f2b(v);
                } else {
                    float res = b2f(feat_res[(size_t)m*CH + co]);
                    int n = m / 49, hw = m - (m/49)*49;
                    size_t off = (size_t)branch*MTOT*CH + ((size_t)n*CH + co)*HW + hw;
                    float o = v + res;
                    if (isf32) ((float*)out_base)[off] = o;
                    else       ((u16*)out_base)[off]   = f2b(o);
                }
            }
        }
    }
}

// ---------------- q conv: spatially-constant 5-ch input ----------------------
// wsum[c] depends only on (hw, co): compute once per thread, amortize over n.
// Grid (HW, 4): blockIdx.y selects a 64-sample n-chunk. 512 threads = co.
__global__ void k_qconv(const u16* __restrict__ status, const u16* __restrict__ rois,
                        const u16* __restrict__ wq, u16* __restrict__ q_t, int branch){
    const int hw = blockIdx.x;
    const int n0 = blockIdx.y * 64;
    const int co = threadIdx.x;          // 512 threads
    const int y = hw / 7, x = hw - (hw/7)*7;

    __shared__ float sv[64][5];
    for (int idx = threadIdx.x; idx < 64*5; idx += 512){
        int n = idx / 5, c = idx - n*5;
        sv[n][c] = (c == 0) ? b2f(status[(n0 + n)*2 + branch])
                            : b2f(rois[(n0 + n)*5 + c]);
    }
    __syncthreads();

    float wsum[5];
#pragma unroll
    for (int c = 0; c < 5; ++c){
        float s = 0.f;
#pragma unroll
        for (int ky = 0; ky < 3; ++ky){
            int yy = y + ky - 1; if (yy < 0 || yy >= 7) continue;
#pragma unroll
            for (int kx = 0; kx < 3; ++kx){
                int xx = x + kx - 1; if (xx < 0 || xx >= 7) continue;
                s += b2f(wq[(co*5 + c)*9 + ky*3 + kx]);
            }
        }
        wsum[c] = s;
    }

    u16* dst = q_t + ((size_t)n0*HW + hw)*CH + co;
    for (int n = 0; n < 64; ++n){
        float acc = sv[n][0]*wsum[0] + sv[n][1]*wsum[1] + sv[n][2]*wsum[2]
                  + sv[n][3]*wsum[3] + sv[n][4]*wsum[4];
        dst[(size_t)n*HW*CH] = f2b(acc);
    }
}

// ---------------- attention per (g, hw) --------------------------------------
__global__ void k_att(const u16* __restrict__ q_t, const u16* __restrict__ k_t,
                      const u16* __restrict__ v_t, u16* __restrict__ virt_t){
    __shared__ u16 qs[16*520], ks[16*520], vs[16*520];
    __shared__ float ls[256], ps[256];
    const int hw = blockIdx.x, g = blockIdx.y;
    const int tid = threadIdx.x;
    for (int idx = tid; idx < 16*512; idx += 256){
        int i = idx >> 9, c = idx & 511;
        size_t m = (size_t)(g*16 + i)*HW + hw;
        qs[i*520 + c] = q_t[m*CH + c];
        ks[i*520 + c] = k_t[m*CH + c];
        vs[i*520 + c] = v_t[m*CH + c];
    }
    __syncthreads();
    const int i = tid >> 4, j = tid & 15;
    float dot = 0.f;
    for (int c = 0; c < 512; ++c) dot += b2f(qs[i*520 + c]) * b2f(ks[j*520 + c]);
    ls[tid] = dot * 0.04419417382415922f;   // 1/sqrt(512)
    __syncthreads();
    float mx = -1e30f;
    for (int jj = 0; jj < 16; ++jj) mx = fmaxf(mx, ls[i*16 + jj]);
    float ssum = 0.f;
    for (int jj = 0; jj < 16; ++jj) ssum += __expf(ls[i*16 + jj] - mx);
    ps[tid] = __expf(ls[tid] - mx) / ssum;
    __syncthreads();
    const int c0 = tid & 15, ii = tid >> 4;
    for (int c = c0; c < 512; c += 16){
        float a = 0.f;
        for (int jj = 0; jj < 16; ++jj) a += ps[ii*16 + jj] * b2f(vs[jj*520 + c]);
        virt_t[((size_t)(g*16 + ii)*HW + hw)*CH + c] = f2b(a);
    }
}

// ---------------- per-sample mean/rstd over 512*49 ---------------------------
__global__ void k_stats(const u16* __restrict__ virt_t, float* __restrict__ stats){
    const int n = blockIdx.x;
    const u16* p = virt_t + (size_t)n * (CH*HW);
    float s = 0.f, s2 = 0.f;
    for (int idx = threadIdx.x; idx < CH*HW; idx += 256){
        float v = b2f(p[idx]); s += v; s2 += v*v;
    }
    for (int off = 32; off; off >>= 1){
        s  += __shfl_down(s,  off, 64);
        s2 += __shfl_down(s2, off, 64);
    }
    __shared__ float bs[4], bs2[4];
    int wave = threadIdx.x >> 6, lane = threadIdx.x & 63;
    if (lane == 0){ bs[wave] = s; bs2[wave] = s2; }
    __syncthreads();
    if (threadIdx.x == 0){
        float t = 0.f, t2 = 0.f;
        for (int w = 0; w < 4; ++w){ t += bs[w]; t2 += bs2[w]; }
        float mean = t / (float)(CH*HW);
        float var  = t2 / (float)(CH*HW) - mean*mean;
        stats[n*2]   = mean;
        stats[n*2+1] = rsqrtf(var + 1e-5f);
    }
}

// ---------------- normalize + relu ------------------------------------------
__global__ void k_norm(const u16* __restrict__ virt_t, const float* __restrict__ stats,
                       const u16* __restrict__ gamma, const u16* __restrict__ beta,
                       u16* __restrict__ h_t){
    size_t idx = (size_t)blockIdx.x*256 + threadIdx.x;
    if (idx >= (size_t)NS*HW*CH) return;
    int c = (int)(idx & 511);
    int m = (int)(idx >> 9);
    int n = m / 49;
    float v = b2f(virt_t[idx]);
    float h = (v - stats[n*2]) * stats[n*2+1] * b2f(gamma[c]) + b2f(beta[c]);
    h_t[idx] = f2b(fmaxf(h, 0.f));
}

extern "C" void kernel_launch(void* const* d_in, const int* in_sizes, int n_in,
                              void* d_out, int out_size, void* d_ws, size_t ws_size,
                              hipStream_t stream) {
    const void* status   = d_in[0];
    const void* rois     = d_in[1];
    const void* bbox     = d_in[2];
    const void* w_reduce = d_in[3];
    const void* w_q1     = d_in[4];
    const void* w_q2     = d_in[5];
    const void* w_k1     = d_in[6];
    const void* w_v1     = d_in[7];
    const void* w_k2     = d_in[8];
    const void* w_v2     = d_in[9];
    const void* w_c1     = d_in[10];
    const void* w_c2     = d_in[11];
    const void* gamma    = d_in[12];
    const void* beta     = d_in[13];

    // ---- workspace layout with aliasing (total ~120.4 MB) ----
    char* p = (char*)d_ws;
    const size_t SZ_INT  = (size_t)MTOT*CIN*2;   // 57,802,752  region0
    const size_t SZ_WRT  = (size_t)CH*9*CIN*2;   // 21,233,664  region1
    const size_t SZ_T    = (size_t)MTOT*CH*2;    // 12,845,056
    const size_t SZ_WT   = (size_t)CH*9*CH*2;    //  4,718,592

    u16* in_t  = (u16*)p;
    u16* w_r_t = (u16*)(p + SZ_INT);
    char* p2   = p + SZ_INT + SZ_WRT;
    u16* wt[6];
    for (int i = 0; i < 6; ++i) wt[i] = (u16*)(p2 + i*SZ_WT);
    u16* feat_t = (u16*)(p2 + 6*SZ_WT);
    char* p3 = p2 + 6*SZ_WT + SZ_T;
    float* stats    = (float*)p3;
    int*   flag     = (int*)(p3 + 4096);
    u16*   status_c = (u16*)(p3 + 8192);
    u16*   rois_c   = status_c + 1024;
    u16*   gamma_c  = rois_c + 2048;
    u16*   beta_c   = gamma_c + 512;
    u16*   wq_c0    = beta_c + 512;
    u16*   wq_c1    = wq_c0 + CH*5*9;
    u16*   zp       = wq_c1 + CH*5*9;     // 8 KB zero page for padding taps
    // aliases into regions dead after the feat conv:
    u16* q_t    = (u16*)p;
    u16* k_t    = (u16*)(p + SZ_T);
    u16* v_t    = (u16*)(p + 2*SZ_T);   // contiguous after k_t (KV-fused writes)
    u16* virt_t = (u16*)(p + 3*SZ_T);   // 4*SZ_T = 51.4MB <= 57.8MB
    u16* h_t    = w_r_t;                // 12.85MB <= 21.2MB

    k_detect<<<1, 256, 0, stream>>>((const u16*)bbox, flag);
    k_zero<<<16, 256, 0, stream>>>(zp, 4096);
    k_transpose_in<<<dim3(NS, CIN/64), 256, 0, stream>>>(bbox, in_t, flag);
    k_transpose_w<<<1024, 256, 0, stream>>>(w_reduce, w_r_t, CIN, flag);
    const void* wsrc[6] = {w_k1, w_v1, w_k2, w_v2, w_c1, w_c2};
    for (int i = 0; i < 6; ++i)
        k_transpose_w<<<512, 256, 0, stream>>>(wsrc[i], wt[i], CH, flag);
    k_convert_small<<<2, 256, 0, stream>>>(status, status_c, NS*2, flag);
    k_convert_small<<<5, 256, 0, stream>>>(rois, rois_c, NS*5, flag);
    k_convert_small<<<2, 256, 0, stream>>>(gamma, gamma_c, CH, flag);
    k_convert_small<<<2, 256, 0, stream>>>(beta, beta_c, CH, flag);
    k_convert_small<<<90, 256, 0, stream>>>(w_q1, wq_c0, CH*5*9, flag);
    k_convert_small<<<90, 256, 0, stream>>>(w_q2, wq_c1, CH*5*9, flag);

    // reduce conv: M=12544, N=512, K=9*2304
    k_conv3x3<<<dim3(MTOT/128, CH/128), 256, 0, stream>>>(
        in_t, w_r_t, CIN, zp, feat_t, nullptr, nullptr, 0, 0, flag);

    for (int br = 0; br < 2; ++br){
        k_qconv<<<dim3(HW, 4), 512, 0, stream>>>(status_c, rois_c,
                                                 br ? wq_c1 : wq_c0, q_t, br);
        // fused K+V conv: N=1024 (wt[br*2],wt[br*2+1] contiguous), writes k_t|v_t
        k_conv3x3<<<dim3(MTOT/128, 1024/128), 256, 0, stream>>>(
            feat_t, wt[br*2], CH, zp, k_t, nullptr, nullptr, 0, 0, flag);
        k_att<<<dim3(HW, 16), 256, 0, stream>>>(q_t, k_t, v_t, virt_t);
        k_stats<<<NS, 256, 0, stream>>>(virt_t, stats);
        k_norm<<<(NS*HW*CH)/256, 256, 0, stream>>>(virt_t, stats, gamma_c, beta_c, h_t);
        k_conv3x3<<<dim3(MTOT/128, CH/128), 256, 0, stream>>>(
            h_t, wt[4 + br], CH, zp, nullptr, feat_t, d_out, 1, br, flag);
    }
}

// Round 4
// 1254.932 us; speedup vs baseline: 6.6678x; 1.0675x over previous
//
#include <hip/hip_runtime.h>
#include <stdint.h>

typedef unsigned short u16;
typedef short short8 __attribute__((ext_vector_type(8)));
typedef float f32x4 __attribute__((ext_vector_type(4)));

#define NS 256
#define CIN 2304
#define CH 512
#define HW 49
#define MTOT (NS*HW)   // 12544

__device__ __forceinline__ float b2f(u16 u){
    union { unsigned int v; float f; } x; x.v = ((unsigned int)u) << 16; return x.f;
}
__device__ __forceinline__ u16 f2b(float f){
    unsigned int u = __builtin_bit_cast(unsigned int, f);
    u += 0x7FFFu + ((u >> 16) & 1u);
    return (u16)(u >> 16);
}
__device__ __forceinline__ u16 load_as_bf16(const void* p, size_t i, int isf32){
    return isf32 ? f2b(((const float*)p)[i]) : ((const u16*)p)[i];
}

// async global->LDS, 16B per lane. Dest is wave-uniform base + lane*16 (HW rule).
__device__ __forceinline__ void gload16(const u16* g, u16* l){
    __builtin_amdgcn_global_load_lds((const __attribute__((address_space(1))) void*)g,
                                     (__attribute__((address_space(3))) void*)l,
                                     16, 0, 0);
}

// ---------------- dtype detector: fp32 mantissa halves have big exponents ----
__global__ void k_detect(const u16* __restrict__ src, int* __restrict__ flag){
    int cnt = 0;
    for (int i = threadIdx.x; i < 8192; i += 256){
        int e = (src[i] >> 7) & 0xFF;
        cnt += (e >= 0x90);
    }
    for (int off = 32; off; off >>= 1) cnt += __shfl_down(cnt, off, 64);
    __shared__ int sh[4];
    int wave = threadIdx.x >> 6, lane = threadIdx.x & 63;
    if (lane == 0) sh[wave] = cnt;
    __syncthreads();
    if (threadIdx.x == 0)
        flag[0] = (sh[0] + sh[1] + sh[2] + sh[3] > 200) ? 1 : 0;
}

// ---------------- zero filler ------------------------------------------------
__global__ void k_zero(u16* __restrict__ p, int n){
    int i = blockIdx.x*256 + threadIdx.x;
    if (i < n) p[i] = 0;
}

// ---------------- small converter (to bf16) ----------------------------------
__global__ void k_convert_small(const void* __restrict__ src, u16* __restrict__ dst,
                                int n, const int* __restrict__ flag){
    const int isf32 = flag[0];
    for (int i = blockIdx.x*256 + threadIdx.x; i < n; i += gridDim.x*256)
        dst[i] = load_as_bf16(src, i, isf32);
}

// ---------------- transpose bbox_feat [n][2304][49] -> in_t [n][49][2304] ----
__global__ void k_transpose_in(const void* __restrict__ src, u16* __restrict__ dst,
                               const int* __restrict__ flag){
    const int isf32 = flag[0];
    __shared__ u16 tile[64*50];
    const int n = blockIdx.x;
    const int c0 = blockIdx.y * 64;
    const size_t sbase = ((size_t)n*CIN + c0)*HW;
    for (int idx = threadIdx.x; idx < 64*49; idx += 256){
        int cc = idx / 49, hw = idx - cc*49;
        tile[cc*50 + hw] = load_as_bf16(src, sbase + cc*HW + hw, isf32);
    }
    __syncthreads();
    u16* d = dst + (size_t)n*HW*CIN + c0;
    for (int idx = threadIdx.x; idx < 49*64; idx += 256){
        int hw = idx >> 6, cc = idx & 63;
        d[(size_t)hw*CIN + cc] = tile[cc*50 + hw];
    }
}

// ---------------- weight transpose [512][Cin][9] -> [512][9][Cin] ------------
__global__ void k_transpose_w(const void* __restrict__ w, u16* __restrict__ wt,
                              int Cin, const int* __restrict__ flag){
    const int isf32 = flag[0];
    size_t total = (size_t)CH * Cin * 9;
    for (size_t d = (size_t)blockIdx.x*blockDim.x + threadIdx.x; d < total;
         d += (size_t)gridDim.x*blockDim.x){
        int c  = (int)(d % Cin);
        size_t t = d / Cin;
        int kk = (int)(t % 9);
        int co = (int)(t / 9);
        wt[d] = load_as_bf16(w, ((size_t)co*Cin + c)*9 + kk, isf32);
    }
}

// ---------------- 3x3 pad-1 conv: implicit GEMM, 2-phase double-buffered -----
// Tile 128x128, BK=64, 4 waves (2x2), 4x4 16x16x32 frags per wave.
// XCD-aware block swizzle (y-major chunks: each XCD owns contiguous M-tiles
// across all N-tiles -> A panel fetched ~once per XCD L2).
// Per K-step: STAGE(next buf) -> COMPUTE(cur buf) -> one __syncthreads().
// mode 0: out_cl[(co>>9)*MTOT*CH + m*CH + (co&511)] = acc   (N up to 2048 fused)
// mode 1: out[branch][n][co][hw] = acc + feat_res[m][co] via LDS re-tile,
//         coalesced along hw. dtype per dtf.
__global__ __launch_bounds__(256, 2) void k_conv3x3(
        const u16* __restrict__ in_t, const u16* __restrict__ w_t, int Cin,
        const u16* __restrict__ zpage,
        u16* __restrict__ out_cl,
        const u16* __restrict__ feat_res, void* __restrict__ out_base,
        int mode, int branch, const int* __restrict__ dtf)
{
    __shared__ __align__(16) u16 SH[4*128*64];   // 64 KB: 4 staging buffers
    u16* const As0 = SH;
    u16* const Bs0 = SH + 128*64;
    u16* const As1 = SH + 2*128*64;
    u16* const Bs1 = SH + 3*128*64;

    const int tid  = threadIdx.x;
    const int wave = tid >> 6, lane = tid & 63;

    // ---- XCD swizzle: dispatch id -> y-major work id, contiguous per XCD ----
    const int nbx = gridDim.x, nby = gridDim.y;
    const int nwg = nbx * nby;                 // all conv grids are %8 == 0
    const int did = blockIdx.x + nbx*blockIdx.y;
    const int id2 = (did & 7) * (nwg >> 3) + (did >> 3);
    const int bx  = id2 / nby;
    const int by  = id2 - bx*nby;
    const int m0  = bx * 128;
    const int co0 = by * 128;

    // ---- loader mapping: thread t covers LDS rows (t>>3)+32s, 16B slot t&7 ----
    const int lr  = tid >> 3;                 // 0..31
    const int sl  = tid & 7;                  // 16B slot within 128B row
    const int swz = (sl ^ (lr & 7)) * 8;      // pre-swizzled source elem offset

    int nA[4], yA[4], xA[4];
#pragma unroll
    for (int s = 0; s < 4; ++s){
        int m = m0 + lr + 32*s;
        nA[s] = m / 49;
        int hw = m - nA[s]*49;
        yA[s] = hw / 7; xA[s] = hw - yA[s]*7;
    }

    // ---- staging state: walks the flattened K dimension (9 taps x Cin) ------
    const u16* aPtr[4];
    const u16* bPtr[4];
#pragma unroll
    for (int s = 0; s < 4; ++s)
        bPtr[s] = w_t + (size_t)(co0 + lr + 32*s)*9*Cin + swz;
    int kkS = 0, c0S = 0;

    auto recompTaps = [&](){
        int dy = kkS/3 - 1, dx = kkS - (kkS/3)*3 - 1;
#pragma unroll
        for (int s = 0; s < 4; ++s){
            int yy = yA[s] + dy, xx = xA[s] + dx;
            bool valid = (yy >= 0) & (yy < 7) & (xx >= 0) & (xx < 7);
            aPtr[s] = valid ? in_t + (size_t)(nA[s]*49 + yy*7 + xx)*Cin + swz
                            : zpage + swz;
        }
    };
    recompTaps();

    int dstOff[4];
#pragma unroll
    for (int s = 0; s < 4; ++s) dstOff[s] = (wave*8 + s*32)*64;

    auto STAGE = [&](u16* A, u16* B){
#pragma unroll
        for (int s = 0; s < 4; ++s){
            gload16(aPtr[s], A + dstOff[s]);
            gload16(bPtr[s], B + dstOff[s]);
        }
    };
    auto ADV = [&](){
#pragma unroll
        for (int s = 0; s < 4; ++s){ aPtr[s] += 64; bPtr[s] += 64; }
        c0S += 64;
        if (c0S == Cin){
            c0S = 0; ++kkS;
            if (kkS < 9) recompTaps();
        }
    };

    f32x4 acc[4][4];
#pragma unroll
    for (int i = 0; i < 4; ++i)
#pragma unroll
        for (int j = 0; j < 4; ++j)
            acc[i][j] = (f32x4){0.f, 0.f, 0.f, 0.f};

    const int wm = (wave & 1) * 64, wn = (wave >> 1) * 64;
    const int rA0 = wm + (lane & 15);
    const int rB0 = wn + (lane & 15);
    const int sl0 = (((lane >> 4)    ) ^ (lane & 7)) * 8;  // k-half 0 slot (elems)
    const int sl1 = ((4 + (lane >> 4)) ^ (lane & 7)) * 8;  // k-half 1 slot

    auto COMPUTE = [&](const u16* A, const u16* B){
        short8 af[4], bf[4];
#pragma unroll
        for (int i = 0; i < 4; ++i) af[i] = *(const short8*)&A[(rA0 + i*16)*64 + sl0];
#pragma unroll
        for (int j = 0; j < 4; ++j) bf[j] = *(const short8*)&B[(rB0 + j*16)*64 + sl0];
#pragma unroll
        for (int i = 0; i < 4; ++i)
#pragma unroll
            for (int j = 0; j < 4; ++j)
                acc[i][j] = __builtin_amdgcn_mfma_f32_16x16x32_bf16(
                                af[i], bf[j], acc[i][j], 0, 0, 0);
#pragma unroll
        for (int i = 0; i < 4; ++i) af[i] = *(const short8*)&A[(rA0 + i*16)*64 + sl1];
#pragma unroll
        for (int j = 0; j < 4; ++j) bf[j] = *(const short8*)&B[(rB0 + j*16)*64 + sl1];
#pragma unroll
        for (int i = 0; i < 4; ++i)
#pragma unroll
            for (int j = 0; j < 4; ++j)
                acc[i][j] = __builtin_amdgcn_mfma_f32_16x16x32_bf16(
                                af[i], bf[j], acc[i][j], 0, 0, 0);
    };

    // ---- pipeline: stage(t) | compute(t-1) overlapped; one barrier per step --
    const int NK = 9 * (Cin >> 6);   // 324 (Cin=2304) or 72 (Cin=512), even
    STAGE(As0, Bs0); ADV();
    __syncthreads();                 // cold drain, once
    for (int t = 0; t < NK; t += 2){
        STAGE(As1, Bs1); ADV();      // step t+1 in flight
        COMPUTE(As0, Bs0);           // step t
        __syncthreads();             // drains As1/Bs1 loads (hidden under compute)
        if (t + 2 < NK){ STAGE(As0, Bs0); ADV(); }
        COMPUTE(As1, Bs1);           // step t+1
        __syncthreads();
    }

    if (mode == 0){
#pragma unroll
        for (int i = 0; i < 4; ++i){
            int mbase = m0 + wm + i*16 + (lane >> 4)*4;
#pragma unroll
            for (int j = 0; j < 4; ++j){
                int co = co0 + wn + j*16 + (lane & 15);
#pragma unroll
                for (int r = 0; r < 4; ++r){
                    int m = mbase + r;
                    out_cl[(size_t)(co >> 9)*((size_t)MTOT*CH)
                           + (size_t)m*CH + (co & 511)] = f2b(acc[i][j][r]);
                }
            }
        }
    } else {
        // LDS re-tile: FO[coj][mi], then write coalesced along hw (m-major).
        const int isf32 = dtf[0];
        float* FO = (float*)SH;      // 128*128 f32 = 64 KB, staging bufs dead
#pragma unroll
        for (int i = 0; i < 4; ++i){
            int mib = wm + i*16 + (lane >> 4)*4;
#pragma unroll
            for (int j = 0; j < 4; ++j){
                int coj = wn + j*16 + (lane & 15);
#pragma unroll
                for (int r = 0; r < 4; ++r){
                    int mi = mib + r;
                    float res = b2f(feat_res[(size_t)(m0 + mi)*CH + co0 + coj]);
                    FO[coj*128 + mi] = acc[i][j][r] + res;
                }
            }
        }
        __syncthreads();
        for (int idx = tid; idx < 128*128; idx += 256){
            int coj = idx >> 7, mi = idx & 127;
            int m = m0 + mi;
            int n = m / 49, hw = m - n*49;
            size_t off = (size_t)branch*MTOT*CH
                       + ((size_t)n*CH + (co0 + coj))*HW + hw;
            float o = FO[coj*128 + mi];
            if (isf32) ((float*)out_base)[off] = o;
            else       ((u16*)out_base)[off]   = f2b(o);
        }
    }
}

// ---------------- q conv: spatially-constant 5-ch input ----------------------
// wsum[c] depends only on (hw, co): compute once per thread, amortize over n.
__global__ void k_qconv(const u16* __restrict__ status, const u16* __restrict__ rois,
                        const u16* __restrict__ wq, u16* __restrict__ q_t, int branch){
    const int hw = blockIdx.x;
    const int n0 = blockIdx.y * 64;
    const int co = threadIdx.x;          // 512 threads
    const int y = hw / 7, x = hw - (hw/7)*7;

    __shared__ float sv[64][5];
    for (int idx = threadIdx.x; idx < 64*5; idx += 512){
        int n = idx / 5, c = idx - n*5;
        sv[n][c] = (c == 0) ? b2f(status[(n0 + n)*2 + branch])
                            : b2f(rois[(n0 + n)*5 + c]);
    }
    __syncthreads();

    float wsum[5];
#pragma unroll
    for (int c = 0; c < 5; ++c){
        float s = 0.f;
#pragma unroll
        for (int ky = 0; ky < 3; ++ky){
            int yy = y + ky - 1; if (yy < 0 || yy >= 7) continue;
#pragma unroll
            for (int kx = 0; kx < 3; ++kx){
                int xx = x + kx - 1; if (xx < 0 || xx >= 7) continue;
                s += b2f(wq[(co*5 + c)*9 + ky*3 + kx]);
            }
        }
        wsum[c] = s;
    }

    u16* dst = q_t + ((size_t)n0*HW + hw)*CH + co;
    for (int n = 0; n < 64; ++n){
        float acc = sv[n][0]*wsum[0] + sv[n][1]*wsum[1] + sv[n][2]*wsum[2]
                  + sv[n][3]*wsum[3] + sv[n][4]*wsum[4];
        dst[(size_t)n*HW*CH] = f2b(acc);
    }
}

// ---------------- attention per (g, hw) --------------------------------------
__global__ void k_att(const u16* __restrict__ q_t, const u16* __restrict__ k_t,
                      const u16* __restrict__ v_t, u16* __restrict__ virt_t){
    __shared__ u16 qs[16*520], ks[16*520], vs[16*520];
    __shared__ float ls[256], ps[256];
    const int hw = blockIdx.x, g = blockIdx.y;
    const int tid = threadIdx.x;
    for (int idx = tid; idx < 16*512; idx += 256){
        int i = idx >> 9, c = idx & 511;
        size_t m = (size_t)(g*16 + i)*HW + hw;
        qs[i*520 + c] = q_t[m*CH + c];
        ks[i*520 + c] = k_t[m*CH + c];
        vs[i*520 + c] = v_t[m*CH + c];
    }
    __syncthreads();
    const int i = tid >> 4, j = tid & 15;
    float dot = 0.f;
    for (int c = 0; c < 512; ++c) dot += b2f(qs[i*520 + c]) * b2f(ks[j*520 + c]);
    ls[tid] = dot * 0.04419417382415922f;   // 1/sqrt(512)
    __syncthreads();
    float mx = -1e30f;
    for (int jj = 0; jj < 16; ++jj) mx = fmaxf(mx, ls[i*16 + jj]);
    float ssum = 0.f;
    for (int jj = 0; jj < 16; ++jj) ssum += __expf(ls[i*16 + jj] - mx);
    ps[tid] = __expf(ls[tid] - mx) / ssum;
    __syncthreads();
    const int c0 = tid & 15, ii = tid >> 4;
    for (int c = c0; c < 512; c += 16){
        float a = 0.f;
        for (int jj = 0; jj < 16; ++jj) a += ps[ii*16 + jj] * b2f(vs[jj*520 + c]);
        virt_t[((size_t)(g*16 + ii)*HW + hw)*CH + c] = f2b(a);
    }
}

// ---------------- per-sample mean/rstd over 512*49 ---------------------------
__global__ void k_stats(const u16* __restrict__ virt_t, float* __restrict__ stats){
    const int n = blockIdx.x;
    const u16* p = virt_t + (size_t)n * (CH*HW);
    float s = 0.f, s2 = 0.f;
    for (int idx = threadIdx.x; idx < CH*HW; idx += 256){
        float v = b2f(p[idx]); s += v; s2 += v*v;
    }
    for (int off = 32; off; off >>= 1){
        s  += __shfl_down(s,  off, 64);
        s2 += __shfl_down(s2, off, 64);
    }
    __shared__ float bs[4], bs2[4];
    int wave = threadIdx.x >> 6, lane = threadIdx.x & 63;
    if (lane == 0){ bs[wave] = s; bs2[wave] = s2; }
    __syncthreads();
    if (threadIdx.x == 0){
        float t = 0.f, t2 = 0.f;
        for (int w = 0; w < 4; ++w){ t += bs[w]; t2 += bs2[w]; }
        float mean = t / (float)(CH*HW);
        float var  = t2 / (float)(CH*HW) - mean*mean;
        stats[n*2]   = mean;
        stats[n*2+1] = rsqrtf(var + 1e-5f);
    }
}

// ---------------- normalize + relu ------------------------------------------
__global__ void k_norm(const u16* __restrict__ virt_t, const float* __restrict__ stats,
                       const u16* __restrict__ gamma, const u16* __restrict__ beta,
                       u16* __restrict__ h_t){
    size_t idx = (size_t)blockIdx.x*256 + threadIdx.x;
    if (idx >= (size_t)NS*HW*CH) return;
    int c = (int)(idx & 511);
    int m = (int)(idx >> 9);
    int n = m / 49;
    float v = b2f(virt_t[idx]);
    float h = (v - stats[n*2]) * stats[n*2+1] * b2f(gamma[c]) + b2f(beta[c]);
    h_t[idx] = f2b(fmaxf(h, 0.f));
}

extern "C" void kernel_launch(void* const* d_in, const int* in_sizes, int n_in,
                              void* d_out, int out_size, void* d_ws, size_t ws_size,
                              hipStream_t stream) {
    const void* status   = d_in[0];
    const void* rois     = d_in[1];
    const void* bbox     = d_in[2];
    const void* w_reduce = d_in[3];
    const void* w_q1     = d_in[4];
    const void* w_q2     = d_in[5];
    const void* w_k1     = d_in[6];
    const void* w_v1     = d_in[7];
    const void* w_k2     = d_in[8];
    const void* w_v2     = d_in[9];
    const void* w_c1     = d_in[10];
    const void* w_c2     = d_in[11];
    const void* gamma    = d_in[12];
    const void* beta     = d_in[13];

    // ---- workspace layout with aliasing (total ~120.4 MB) ----
    char* p = (char*)d_ws;
    const size_t SZ_INT  = (size_t)MTOT*CIN*2;   // 57,802,752  region0
    const size_t SZ_WRT  = (size_t)CH*9*CIN*2;   // 21,233,664  region1
    const size_t SZ_T    = (size_t)MTOT*CH*2;    // 12,845,056
    const size_t SZ_WT   = (size_t)CH*9*CH*2;    //  4,718,592

    u16* in_t  = (u16*)p;
    u16* w_r_t = (u16*)(p + SZ_INT);
    char* p2   = p + SZ_INT + SZ_WRT;
    u16* wt[6];
    for (int i = 0; i < 6; ++i) wt[i] = (u16*)(p2 + i*SZ_WT);
    u16* feat_t = (u16*)(p2 + 6*SZ_WT);
    char* p3 = p2 + 6*SZ_WT + SZ_T;
    float* stats    = (float*)p3;
    int*   flag     = (int*)(p3 + 4096);
    u16*   status_c = (u16*)(p3 + 8192);
    u16*   rois_c   = status_c + 1024;
    u16*   gamma_c  = rois_c + 2048;
    u16*   beta_c   = gamma_c + 512;
    u16*   wq_c0    = beta_c + 512;
    u16*   wq_c1    = wq_c0 + CH*5*9;
    u16*   zp       = wq_c1 + CH*5*9;     // 8 KB zero page for padding taps
    // aliases into region0+region1 (79.0 MB dead after the reduce conv):
    // kv4 = k1|v1|k2|v2 (4*SZ_T = 51.4MB), q (SZ_T), virt (SZ_T) -> 77.1MB OK
    u16* kv4    = (u16*)p;
    u16* q_t    = (u16*)(p + 4*SZ_T);
    u16* virt_t = (u16*)(p + 5*SZ_T);
    // h aliases wt[0..3] (18.9MB, dead after the fused KV conv):
    u16* h_t    = (u16*)p2;

    k_detect<<<1, 256, 0, stream>>>((const u16*)bbox, flag);
    k_zero<<<16, 256, 0, stream>>>(zp, 4096);
    k_transpose_in<<<dim3(NS, CIN/64), 256, 0, stream>>>(bbox, in_t, flag);
    k_transpose_w<<<1024, 256, 0, stream>>>(w_reduce, w_r_t, CIN, flag);
    const void* wsrc[6] = {w_k1, w_v1, w_k2, w_v2, w_c1, w_c2};
    for (int i = 0; i < 6; ++i)
        k_transpose_w<<<512, 256, 0, stream>>>(wsrc[i], wt[i], CH, flag);
    k_convert_small<<<2, 256, 0, stream>>>(status, status_c, NS*2, flag);
    k_convert_small<<<5, 256, 0, stream>>>(rois, rois_c, NS*5, flag);
    k_convert_small<<<2, 256, 0, stream>>>(gamma, gamma_c, CH, flag);
    k_convert_small<<<2, 256, 0, stream>>>(beta, beta_c, CH, flag);
    k_convert_small<<<90, 256, 0, stream>>>(w_q1, wq_c0, CH*5*9, flag);
    k_convert_small<<<90, 256, 0, stream>>>(w_q2, wq_c1, CH*5*9, flag);

    // reduce conv: M=12544, N=512, K=9*2304  (grid 392 = 8*49)
    k_conv3x3<<<dim3(MTOT/128, CH/128), 256, 0, stream>>>(
        in_t, w_r_t, CIN, zp, feat_t, nullptr, nullptr, 0, 0, flag);

    // fused K+V conv for BOTH branches: N=2048 (wt[0..3] contiguous),
    // writes kv4 = k1|v1|k2|v2.  grid 1568 = 8*196
    k_conv3x3<<<dim3(MTOT/128, 2048/128), 256, 0, stream>>>(
        feat_t, wt[0], CH, zp, kv4, nullptr, nullptr, 0, 0, flag);

    for (int br = 0; br < 2; ++br){
        k_qconv<<<dim3(HW, 4), 512, 0, stream>>>(status_c, rois_c,
                                                 br ? wq_c1 : wq_c0, q_t, br);
        k_att<<<dim3(HW, 16), 256, 0, stream>>>(
            q_t, kv4 + (size_t)(2*br)*MTOT*CH, kv4 + (size_t)(2*br+1)*MTOT*CH,
            virt_t);
        k_stats<<<NS, 256, 0, stream>>>(virt_t, stats);
        k_norm<<<(NS*HW*CH)/256, 256, 0, stream>>>(virt_t, stats, gamma_c, beta_c, h_t);
        k_conv3x3<<<dim3(MTOT/128, CH/128), 256, 0, stream>>>(
            h_t, wt[4 + br], CH, zp, nullptr, feat_t, d_out, 1, br, flag);
    }
}